// Round 14
// baseline (73.631 us; speedup 1.0000x reference)
//
#include <hip/hip_runtime.h>

// PointPillars voxelization, MI355X. Output FLOAT32 flat concat:
//   voxels [40000][32][8], coords [40000][3] (z,y,x), num_points [40000].
// Input float32 [N][8]. PASSED r6-r13 (absmax 0) with binning:
//   cx=floor(x*6.25f), cy=floor((y+39.68f)*6.25f), cz=floor((z+3.f)*0.25f)
// (XLA div-by-const -> mul-by-reciprocal, f32 RN). DO NOT CHANGE BINNING.
//
// r14: MEASUREMENT ROUND #2 (emit). Slots moved out->ws so emit4 is pure
// (read ws slots -> write out); emit4 node DUPLICATED; dur - ~57 = emit cost.
// Known: prep = 9.5us wall (r12). Suspects: append2+emit4 ~30-35us vs ~18
// modeled. Chain: zero -> prep2 -> blocksum2 -> ranks3 -> append2 -> emit4
// -> emit4.

constexpr int NXv = 432;
constexpr int NYv = 496;
constexpr int NZv = 1;
constexpr int NVOX = NXv * NYv * NZv;      // 214272
constexpr int MAX_PTSv = 32;
constexpr int MAX_VOXv = 40000;
constexpr int SLOT_CAP = 64;
constexpr int SCAN_BS = 256;
constexpr int NBLK = NVOX / SCAN_BS;       // 837 exact

constexpr size_t VOX_F   = (size_t)MAX_VOXv * MAX_PTSv * 8;  // 10,240,000 f32
constexpr size_t COORD_F = (size_t)MAX_VOXv * 3;             // 120,000 f32

__device__ __forceinline__ int voxel_id(float x, float y, float z) {
    float fx = x * 6.25f;
    float fy = (y + 39.68f) * 6.25f;
    float fz = (z + 3.0f) * 0.25f;
    int cx = (int)floorf(fx);
    int cy = (int)floorf(fy);
    int cz = (int)floorf(fz);
    if (cx < 0 || cx >= NXv || cy < 0 || cy >= NYv || cz < 0 || cz >= NZv)
        return -1;
    return (cz * NYv + cy) * NXv + cx;
}

__global__ void k_zero(unsigned int* p, int n) {
    int i = blockIdx.x * blockDim.x + threadIdx.x;
    int stride = gridDim.x * blockDim.x;
    for (; i < n; i += stride) p[i] = 0u;
}

// ---------- fast path ----------

// 2 points per thread: contiguous reads, int2 vids write
__global__ void k_prep2(const float* __restrict__ pf, int N,
                        int* __restrict__ vids, unsigned char* __restrict__ occ) {
    int i = blockIdx.x * blockDim.x + threadIdx.x;   // pair index
    int p0 = i * 2;
    if (p0 >= N) return;
    const float4* p4 = reinterpret_cast<const float4*>(pf);
    float4 a = p4[(size_t)p0 * 2];
    int v0 = voxel_id(a.x, a.y, a.z);
    if (p0 + 1 < N) {
        float4 b = p4[(size_t)p0 * 2 + 2];
        int v1 = voxel_id(b.x, b.y, b.z);
        *reinterpret_cast<int2*>(vids + p0) = make_int2(v0, v1);
        if (v1 >= 0) occ[v1] = 1;
    } else {
        vids[p0] = v0;
    }
    if (v0 >= 0) occ[v0] = 1;
}

// blocksum over occ + zero appcnt slice (before append2 by kernel order)
__global__ void k_blocksum2(const unsigned char* __restrict__ occ,
                            unsigned int* __restrict__ bsums,
                            unsigned int* __restrict__ appcnt) {
    int i = blockIdx.x * SCAN_BS + threadIdx.x;
    if (i < MAX_VOXv) appcnt[i] = 0u;
    int flag = (occ[i] != 0) ? 1 : 0;
    unsigned long long b = __ballot(flag);
    __shared__ unsigned int wsum[SCAN_BS / 64];
    if ((threadIdx.x & 63) == 0) wsum[threadIdx.x >> 6] = (unsigned)__popcll(b);
    __syncthreads();
    if (threadIdx.x == 0) {
        unsigned s = 0;
        for (int w = 0; w < SCAN_BS / 64; ++w) s += wsum[w];
        bsums[blockIdx.x] = s;
    }
}

__global__ void k_ranks3(const unsigned char* __restrict__ occ,
                         const unsigned int* __restrict__ bsums,
                         unsigned int* __restrict__ scal,
                         int* __restrict__ rank_of,
                         int* __restrict__ vid_of_rank) {
    const int vb = blockIdx.x;
    const int t = threadIdx.x;
    __shared__ unsigned int pr[SCAN_BS];
    __shared__ unsigned int sh[SCAN_BS];

    unsigned p = 0;
    for (int j = t; j < vb; j += SCAN_BS) p += bsums[j];
    pr[t] = p;
    __syncthreads();
    for (int off = SCAN_BS / 2; off >= 1; off >>= 1) {
        if (t < off) pr[t] += pr[t + off];
        __syncthreads();
    }
    unsigned excl = pr[0];

    int i = vb * SCAN_BS + t;
    int flag = (occ[i] != 0) ? 1 : 0;
    sh[t] = (unsigned)flag;
    __syncthreads();
    for (int off = 1; off < SCAN_BS; off <<= 1) {
        unsigned add = (t >= off) ? sh[t - off] : 0u;
        __syncthreads();
        sh[t] += add;
        __syncthreads();
    }
    unsigned rank = excl + sh[t] - (unsigned)flag;
    int r = (flag && rank < (unsigned)MAX_VOXv) ? (int)rank : -1;
    rank_of[i] = r;
    if (r >= 0) vid_of_rank[r] = i;
    if (vb == NBLK - 1 && t == SCAN_BS - 1) scal[0] = excl + sh[t];
}

// append into ws slot array (NOT the out rows)
__global__ void k_append2(const int* __restrict__ vids, int N,
                          const int* __restrict__ rank_of,
                          unsigned int* __restrict__ appcnt,
                          int* __restrict__ slots) {
    int i = blockIdx.x * blockDim.x + threadIdx.x;
    if (i >= N) return;
    int vid = vids[i];
    if (vid < 0) return;
    int r = rank_of[vid];
    if (r < 0) return;
    unsigned s = atomicAdd(&appcnt[r], 1u);
    if (s < (unsigned)SLOT_CAP) slots[(size_t)r * SLOT_CAP + s] = i;
}

// emit: 4 rows per 256-thread block; PURE (reads ws, writes every out byte)
__global__ void k_emit4(const float* __restrict__ pf,
                        const unsigned int* __restrict__ appcnt,
                        const int* __restrict__ slots,
                        const int* __restrict__ vid_of_rank,
                        const unsigned int* __restrict__ scal,
                        float* __restrict__ out) {
    const int t = threadIdx.x;
    const int sub = t >> 6;
    const int lane = t & 63;
    const int r = blockIdx.x * 4 + sub;
    float* out_coord = out + VOX_F;
    float* out_num   = out + VOX_F + COORD_F;
    unsigned K = min(scal[0], (unsigned)MAX_VOXv);
    float* row = out + (size_t)r * (MAX_PTSv * 8);

    __shared__ int sidx[4][64];
    bool isocc = (unsigned)r < K;
    int c = 0;
    if (isocc) c = (int)min(appcnt[r], (unsigned)SLOT_CAP);
    sidx[sub][lane] = (lane < c) ? slots[(size_t)r * SLOT_CAP + lane] : 0x7fffffff;
    __syncthreads();

    if (isocc) {
        int nkeep = c < MAX_PTSv ? c : MAX_PTSv;
        if (lane < c) {
            int my = sidx[sub][lane];
            int pos = 0;
            for (int j = 0; j < c; ++j) pos += (sidx[sub][j] < my) ? 1 : 0;
            if (pos < MAX_PTSv) {
                const float4* src =
                    reinterpret_cast<const float4*>(pf) + (size_t)my * 2;
                float4 a = src[0];
                float4 b = src[1];
                float4* dst = reinterpret_cast<float4*>(row + pos * 8);
                dst[0] = a;
                dst[1] = b;
            }
        }
        if (lane >= nkeep && lane < MAX_PTSv) {
            float4* dst = reinterpret_cast<float4*>(row + lane * 8);
            dst[0] = make_float4(0.f, 0.f, 0.f, 0.f);
            dst[1] = make_float4(0.f, 0.f, 0.f, 0.f);
        }
        if (lane == 0) {
            int vid = vid_of_rank[r];
            int vx = vid % NXv;
            int vy = (vid / NXv) % NYv;
            int vz = vid / (NXv * NYv);
            out_coord[(size_t)r * 3 + 0] = (float)vz;
            out_coord[(size_t)r * 3 + 1] = (float)vy;
            out_coord[(size_t)r * 3 + 2] = (float)vx;
            out_num[r] = (float)nkeep;
        }
    } else {
        reinterpret_cast<float4*>(row)[lane] = make_float4(0.f, 0.f, 0.f, 0.f);
        if (lane == 0) {
            out_coord[(size_t)r * 3 + 0] = 0.f;
            out_coord[(size_t)r * 3 + 1] = 0.f;
            out_coord[(size_t)r * 3 + 2] = 0.f;
            out_num[r] = 0.f;
        }
    }
}

// ---------- fallback path (r6 proven, 7 kernels) ----------

__global__ void k_count(const float* __restrict__ pf, int N,
                        unsigned int* __restrict__ counts) {
    int i = blockIdx.x * blockDim.x + threadIdx.x;
    if (i >= N) return;
    float4 v = reinterpret_cast<const float4*>(pf)[(size_t)i * 2];
    int vid = voxel_id(v.x, v.y, v.z);
    if (vid >= 0) atomicAdd(&counts[vid], 1u);
}

__global__ void k_blocksum(const unsigned int* __restrict__ counts,
                           unsigned int* __restrict__ bsums) {
    int i = blockIdx.x * SCAN_BS + threadIdx.x;
    int flag = (counts[i] != 0u) ? 1 : 0;
    unsigned long long b = __ballot(flag);
    __shared__ unsigned int wsum[SCAN_BS / 64];
    if ((threadIdx.x & 63) == 0) wsum[threadIdx.x >> 6] = (unsigned)__popcll(b);
    __syncthreads();
    if (threadIdx.x == 0) {
        unsigned s = 0;
        for (int w = 0; w < SCAN_BS / 64; ++w) s += wsum[w];
        bsums[blockIdx.x] = s;
    }
}

__global__ void k_scan_bsums(unsigned int* __restrict__ bsums,
                             unsigned int* __restrict__ scal) {
    __shared__ unsigned int sh[1024];
    int t = threadIdx.x;
    unsigned v = (t < NBLK) ? bsums[t] : 0u;
    sh[t] = v;
    __syncthreads();
    for (int off = 1; off < 1024; off <<= 1) {
        unsigned add = (t >= off) ? sh[t - off] : 0u;
        __syncthreads();
        sh[t] += add;
        __syncthreads();
    }
    if (t < NBLK) bsums[t] = sh[t] - v;
    if (t == NBLK - 1) scal[0] = sh[t];
}

__global__ void k_ranks(const unsigned int* __restrict__ counts,
                        const unsigned int* __restrict__ bsums,
                        int* __restrict__ rank_of, int* __restrict__ vid_of_rank) {
    int i = blockIdx.x * SCAN_BS + threadIdx.x;
    int t = threadIdx.x;
    int flag = (counts[i] != 0u) ? 1 : 0;
    __shared__ unsigned int sh[SCAN_BS];
    sh[t] = (unsigned)flag;
    __syncthreads();
    for (int off = 1; off < SCAN_BS; off <<= 1) {
        unsigned add = (t >= off) ? sh[t - off] : 0u;
        __syncthreads();
        sh[t] += add;
        __syncthreads();
    }
    unsigned rank = bsums[blockIdx.x] + sh[t] - (unsigned)flag;
    int r = (flag && rank < (unsigned)MAX_VOXv) ? (int)rank : -1;
    rank_of[i] = r;
    if (r >= 0) vid_of_rank[r] = i;
}

__global__ void k_append(const float* __restrict__ pf, int N,
                         const int* __restrict__ rank_of,
                         unsigned int* __restrict__ appcnt,
                         float* __restrict__ out) {
    int i = blockIdx.x * blockDim.x + threadIdx.x;
    if (i >= N) return;
    float4 v = reinterpret_cast<const float4*>(pf)[(size_t)i * 2];
    int vid = voxel_id(v.x, v.y, v.z);
    if (vid < 0) return;
    int r = rank_of[vid];
    if (r < 0) return;
    unsigned s = atomicAdd(&appcnt[r], 1u);
    if (s < (unsigned)SLOT_CAP) {
        int* rowi = reinterpret_cast<int*>(out + (size_t)r * (MAX_PTSv * 8));
        rowi[s] = i;
    }
}

__global__ void k_emit(const float* __restrict__ pf,
                       const unsigned int* __restrict__ appcnt,
                       const int* __restrict__ vid_of_rank,
                       const unsigned int* __restrict__ scal,
                       float* __restrict__ out) {
    int r = blockIdx.x;
    int t = threadIdx.x;
    float* row       = out + (size_t)r * (MAX_PTSv * 8);
    float* out_coord = out + VOX_F;
    float* out_num   = out + VOX_F + COORD_F;
    unsigned K = min(scal[0], (unsigned)MAX_VOXv);

    if ((unsigned)r >= K) {
        reinterpret_cast<float4*>(row)[t] = make_float4(0.f, 0.f, 0.f, 0.f);
        if (t == 0) {
            out_coord[(size_t)r * 3 + 0] = 0.f;
            out_coord[(size_t)r * 3 + 1] = 0.f;
            out_coord[(size_t)r * 3 + 2] = 0.f;
            out_num[r] = 0.f;
        }
        return;
    }

    __shared__ int sidx[SLOT_CAP];
    int c = (int)min(appcnt[r], (unsigned)SLOT_CAP);
    const int* rowi = reinterpret_cast<const int*>(row);
    sidx[t] = (t < c) ? rowi[t] : 0x7fffffff;
    __syncthreads();
    int nkeep = c < MAX_PTSv ? c : MAX_PTSv;

    if (t < c) {
        int my = sidx[t];
        int pos = 0;
        for (int j = 0; j < c; ++j) pos += (sidx[j] < my) ? 1 : 0;
        if (pos < MAX_PTSv) {
            const float4* src = reinterpret_cast<const float4*>(pf) + (size_t)my * 2;
            float4 a = src[0];
            float4 b = src[1];
            float4* dst = reinterpret_cast<float4*>(row + pos * 8);
            dst[0] = a;
            dst[1] = b;
        }
    }
    if (t >= nkeep && t < MAX_PTSv) {
        float4* dst = reinterpret_cast<float4*>(row + t * 8);
        dst[0] = make_float4(0.f, 0.f, 0.f, 0.f);
        dst[1] = make_float4(0.f, 0.f, 0.f, 0.f);
    }
    if (t == 0) {
        int vid = vid_of_rank[r];
        int vx = vid % NXv;
        int vy = (vid / NXv) % NYv;
        int vz = vid / (NXv * NYv);
        out_coord[(size_t)r * 3 + 0] = (float)vz;
        out_coord[(size_t)r * 3 + 1] = (float)vy;
        out_coord[(size_t)r * 3 + 2] = (float)vx;
        out_num[r] = (float)nkeep;
    }
}

extern "C" void kernel_launch(void* const* d_in, const int* in_sizes, int n_in,
                              void* d_out, int out_size, void* d_ws, size_t ws_size,
                              hipStream_t stream) {
    const float* pf = (const float*)d_in[0];
    const int N = in_sizes[0] / 8;
    float* out = (float*)d_out;

    // fast-path ws layout (bytes):
    //   [occ u8 215040]           <- zeroed by k_zero
    //   [appcnt u32 160000]       <- zeroed inside blocksum2
    //   [scal 64]                 <- plain store by ranks3
    //   [bsums 4096][rank_of NVOX*4][vid_of_rank MAX_VOX*4][vids N*4]
    //   [slots MAX_VOX*64*4 = 10.24MB]
    const size_t OCC_B  = 215040;
    const size_t APP_B  = (size_t)MAX_VOXv * 4;
    const size_t SCAL_B = 64;
    const size_t HEAD_B = OCC_B + APP_B + SCAL_B;
    const size_t BS_B   = 4096;
    const size_t RANK_B = (size_t)NVOX * 4;
    const size_t VOR_B  = (size_t)MAX_VOXv * 4;
    const size_t VIDS_B = (size_t)N * 4;
    const size_t SLOT_B = (size_t)MAX_VOXv * SLOT_CAP * 4;
    const size_t NEED   = HEAD_B + BS_B + RANK_B + VOR_B + VIDS_B + SLOT_B;

    char* wsb = (char*)d_ws;
    unsigned char* occ        = (unsigned char*)wsb;
    unsigned int* appcnt      = (unsigned int*)(wsb + OCC_B);
    unsigned int* scal        = (unsigned int*)(wsb + OCC_B + APP_B);
    unsigned int* bsums       = (unsigned int*)(wsb + HEAD_B);
    int*          rank_of     = (int*)(wsb + HEAD_B + BS_B);
    int*          vid_of_rank = (int*)(wsb + HEAD_B + BS_B + RANK_B);
    int*          vids        = (int*)(wsb + HEAD_B + BS_B + RANK_B + VOR_B);
    int*          slots       = (int*)(wsb + HEAD_B + BS_B + RANK_B + VOR_B + VIDS_B);

    if (ws_size >= NEED) {
        k_zero<<<210, 256, 0, stream>>>((unsigned int*)occ, (int)(OCC_B / 4));
        k_prep2<<<((N + 1) / 2 + 255) / 256, 256, 0, stream>>>(pf, N, vids, occ);
        k_blocksum2<<<NBLK, SCAN_BS, 0, stream>>>(occ, bsums, appcnt);
        k_ranks3<<<NBLK, SCAN_BS, 0, stream>>>(occ, bsums, scal, rank_of, vid_of_rank);
        k_append2<<<(N + 255) / 256, 256, 0, stream>>>(vids, N, rank_of, appcnt, slots);
        k_emit4<<<MAX_VOXv / 4, SCAN_BS, 0, stream>>>(pf, appcnt, slots, vid_of_rank, scal, out);
        // MEASUREMENT: emit4 is pure (ws -> out); duplicate == one emit4 cost
        k_emit4<<<MAX_VOXv / 4, SCAN_BS, 0, stream>>>(pf, appcnt, slots, vid_of_rank, scal, out);
        return;
    }

    // fallback: r6 proven layout/path (~2.04 MB)
    unsigned int* wsp          = (unsigned int*)d_ws;
    unsigned int* counts_f     = wsp;
    unsigned int* appcnt_f     = counts_f + NVOX;
    unsigned int* bsums_f      = appcnt_f + MAX_VOXv;
    unsigned int* scal_f       = bsums_f + 1024;
    int*          rank_of_f    = (int*)(scal_f + 4);
    int*          vid_of_rk_f  = rank_of_f + NVOX;

    const int n_zero = NVOX + MAX_VOXv + 1024 + 4;
    k_zero<<<512, 256, 0, stream>>>(wsp, n_zero);
    k_count<<<(N + 255) / 256, 256, 0, stream>>>(pf, N, counts_f);
    k_blocksum<<<NBLK, SCAN_BS, 0, stream>>>(counts_f, bsums_f);
    k_scan_bsums<<<1, 1024, 0, stream>>>(bsums_f, scal_f);
    k_ranks<<<NBLK, SCAN_BS, 0, stream>>>(counts_f, bsums_f, rank_of_f, vid_of_rk_f);
    k_append<<<(N + 255) / 256, 256, 0, stream>>>(pf, N, rank_of_f, appcnt_f, out);
    k_emit<<<MAX_VOXv, 64, 0, stream>>>(pf, appcnt_f, vid_of_rk_f, scal_f, out);
}

// Round 15
// 56.377 us; speedup vs baseline: 1.3060x; 1.3060x over previous
//
#include <hip/hip_runtime.h>

// PointPillars voxelization, MI355X. Output FLOAT32 flat concat:
//   voxels [40000][32][8], coords [40000][3] (z,y,x), num_points [40000].
// Input float32 [N][8]. PASSED r6-r14 (absmax 0) with binning:
//   cx=floor(x*6.25f), cy=floor((y+39.68f)*6.25f), cz=floor((z+3.f)*0.25f)
// (XLA div-by-const -> mul-by-reciprocal, f32 RN). DO NOT CHANGE BINNING.
//
// Measured budget (duplicate-node probes): prep2 = 9.5us (r12),
// emit4 = 16.4us (r14), append2 ~ 11-14us, scan ~6us, gaps ~10us.
// r15: emit write-phase rewrite -- inverse permutation in LDS, all 64 lanes
// store 16B each (one coalesced 1024B wave store per row), nontemporal
// stores for all output (out is never re-read; keeps L2 for occ/rank
// tables). Everything else identical to r14 (duplicate emit removed).

constexpr int NXv = 432;
constexpr int NYv = 496;
constexpr int NZv = 1;
constexpr int NVOX = NXv * NYv * NZv;      // 214272
constexpr int MAX_PTSv = 32;
constexpr int MAX_VOXv = 40000;
constexpr int SLOT_CAP = 64;
constexpr int SCAN_BS = 256;
constexpr int NBLK = NVOX / SCAN_BS;       // 837 exact

constexpr size_t VOX_F   = (size_t)MAX_VOXv * MAX_PTSv * 8;  // 10,240,000 f32
constexpr size_t COORD_F = (size_t)MAX_VOXv * 3;             // 120,000 f32

typedef float f32x4 __attribute__((ext_vector_type(4)));

__device__ __forceinline__ int voxel_id(float x, float y, float z) {
    float fx = x * 6.25f;
    float fy = (y + 39.68f) * 6.25f;
    float fz = (z + 3.0f) * 0.25f;
    int cx = (int)floorf(fx);
    int cy = (int)floorf(fy);
    int cz = (int)floorf(fz);
    if (cx < 0 || cx >= NXv || cy < 0 || cy >= NYv || cz < 0 || cz >= NZv)
        return -1;
    return (cz * NYv + cy) * NXv + cx;
}

__global__ void k_zero(unsigned int* p, int n) {
    int i = blockIdx.x * blockDim.x + threadIdx.x;
    int stride = gridDim.x * blockDim.x;
    for (; i < n; i += stride) p[i] = 0u;
}

// ---------- fast path ----------

// 2 points per thread: contiguous reads, int2 vids write
__global__ void k_prep2(const float* __restrict__ pf, int N,
                        int* __restrict__ vids, unsigned char* __restrict__ occ) {
    int i = blockIdx.x * blockDim.x + threadIdx.x;   // pair index
    int p0 = i * 2;
    if (p0 >= N) return;
    const float4* p4 = reinterpret_cast<const float4*>(pf);
    float4 a = p4[(size_t)p0 * 2];
    int v0 = voxel_id(a.x, a.y, a.z);
    if (p0 + 1 < N) {
        float4 b = p4[(size_t)p0 * 2 + 2];
        int v1 = voxel_id(b.x, b.y, b.z);
        *reinterpret_cast<int2*>(vids + p0) = make_int2(v0, v1);
        if (v1 >= 0) occ[v1] = 1;
    } else {
        vids[p0] = v0;
    }
    if (v0 >= 0) occ[v0] = 1;
}

// blocksum over occ + zero appcnt slice (before append2 by kernel order)
__global__ void k_blocksum2(const unsigned char* __restrict__ occ,
                            unsigned int* __restrict__ bsums,
                            unsigned int* __restrict__ appcnt) {
    int i = blockIdx.x * SCAN_BS + threadIdx.x;
    if (i < MAX_VOXv) appcnt[i] = 0u;
    int flag = (occ[i] != 0) ? 1 : 0;
    unsigned long long b = __ballot(flag);
    __shared__ unsigned int wsum[SCAN_BS / 64];
    if ((threadIdx.x & 63) == 0) wsum[threadIdx.x >> 6] = (unsigned)__popcll(b);
    __syncthreads();
    if (threadIdx.x == 0) {
        unsigned s = 0;
        for (int w = 0; w < SCAN_BS / 64; ++w) s += wsum[w];
        bsums[blockIdx.x] = s;
    }
}

__global__ void k_ranks3(const unsigned char* __restrict__ occ,
                         const unsigned int* __restrict__ bsums,
                         unsigned int* __restrict__ scal,
                         int* __restrict__ rank_of,
                         int* __restrict__ vid_of_rank) {
    const int vb = blockIdx.x;
    const int t = threadIdx.x;
    __shared__ unsigned int pr[SCAN_BS];
    __shared__ unsigned int sh[SCAN_BS];

    unsigned p = 0;
    for (int j = t; j < vb; j += SCAN_BS) p += bsums[j];
    pr[t] = p;
    __syncthreads();
    for (int off = SCAN_BS / 2; off >= 1; off >>= 1) {
        if (t < off) pr[t] += pr[t + off];
        __syncthreads();
    }
    unsigned excl = pr[0];

    int i = vb * SCAN_BS + t;
    int flag = (occ[i] != 0) ? 1 : 0;
    sh[t] = (unsigned)flag;
    __syncthreads();
    for (int off = 1; off < SCAN_BS; off <<= 1) {
        unsigned add = (t >= off) ? sh[t - off] : 0u;
        __syncthreads();
        sh[t] += add;
        __syncthreads();
    }
    unsigned rank = excl + sh[t] - (unsigned)flag;
    int r = (flag && rank < (unsigned)MAX_VOXv) ? (int)rank : -1;
    rank_of[i] = r;
    if (r >= 0) vid_of_rank[r] = i;
    if (vb == NBLK - 1 && t == SCAN_BS - 1) scal[0] = excl + sh[t];
}

// append into ws slot array
__global__ void k_append2(const int* __restrict__ vids, int N,
                          const int* __restrict__ rank_of,
                          unsigned int* __restrict__ appcnt,
                          int* __restrict__ slots) {
    int i = blockIdx.x * blockDim.x + threadIdx.x;
    if (i >= N) return;
    int vid = vids[i];
    if (vid < 0) return;
    int r = rank_of[vid];
    if (r < 0) return;
    unsigned s = atomicAdd(&appcnt[r], 1u);
    if (s < (unsigned)SLOT_CAP) slots[(size_t)r * SLOT_CAP + s] = i;
}

// emit: 4 rows per 256-thread block. Inverse-perm in LDS -> all 64 lanes
// write one 16B chunk (coalesced 1024B wave store), nontemporal stores.
__global__ void k_emit4(const float* __restrict__ pf,
                        const unsigned int* __restrict__ appcnt,
                        const int* __restrict__ slots,
                        const int* __restrict__ vid_of_rank,
                        const unsigned int* __restrict__ scal,
                        float* __restrict__ out) {
    const int t = threadIdx.x;
    const int sub = t >> 6;
    const int lane = t & 63;
    const int r = blockIdx.x * 4 + sub;
    float* out_coord = out + VOX_F;
    float* out_num   = out + VOX_F + COORD_F;
    unsigned K = min(scal[0], (unsigned)MAX_VOXv);
    float* row = out + (size_t)r * (MAX_PTSv * 8);

    __shared__ int sidx[4][SLOT_CAP];
    __shared__ int sinv[4][MAX_PTSv];

    bool isocc = (unsigned)r < K;
    int c = isocc ? (int)min(appcnt[r], (unsigned)SLOT_CAP) : 0;
    if (lane < MAX_PTSv) sinv[sub][lane] = -1;
    sidx[sub][lane] = (lane < c) ? slots[(size_t)r * SLOT_CAP + lane] : 0x7fffffff;
    __syncthreads();

    if (lane < c) {
        int my = sidx[sub][lane];
        int pos = 0;
        for (int j = 0; j < c; ++j) pos += (sidx[sub][j] < my) ? 1 : 0;
        if (pos < MAX_PTSv) sinv[sub][pos] = my;       // stable inverse perm
    }
    __syncthreads();

    // write phase: lane j -> slot j>>1, half j&1; full wave = 1024B row
    int s = lane >> 1;
    int h = lane & 1;
    int src = sinv[sub][s];
    f32x4 w = {0.f, 0.f, 0.f, 0.f};
    if (src >= 0)
        w = *(reinterpret_cast<const f32x4*>(pf) + (size_t)src * 2 + h);
    __builtin_nontemporal_store(w, reinterpret_cast<f32x4*>(row) + s * 2 + h);

    if (lane == 0) {
        if (isocc) {
            int nkeep = c < MAX_PTSv ? c : MAX_PTSv;
            int vid = vid_of_rank[r];
            int vx = vid % NXv;
            int vy = (vid / NXv) % NYv;
            int vz = vid / (NXv * NYv);
            __builtin_nontemporal_store((float)vz, &out_coord[(size_t)r * 3 + 0]);
            __builtin_nontemporal_store((float)vy, &out_coord[(size_t)r * 3 + 1]);
            __builtin_nontemporal_store((float)vx, &out_coord[(size_t)r * 3 + 2]);
            __builtin_nontemporal_store((float)nkeep, &out_num[r]);
        } else {
            __builtin_nontemporal_store(0.f, &out_coord[(size_t)r * 3 + 0]);
            __builtin_nontemporal_store(0.f, &out_coord[(size_t)r * 3 + 1]);
            __builtin_nontemporal_store(0.f, &out_coord[(size_t)r * 3 + 2]);
            __builtin_nontemporal_store(0.f, &out_num[r]);
        }
    }
}

// ---------- fallback path (r6 proven, 7 kernels) ----------

__global__ void k_count(const float* __restrict__ pf, int N,
                        unsigned int* __restrict__ counts) {
    int i = blockIdx.x * blockDim.x + threadIdx.x;
    if (i >= N) return;
    float4 v = reinterpret_cast<const float4*>(pf)[(size_t)i * 2];
    int vid = voxel_id(v.x, v.y, v.z);
    if (vid >= 0) atomicAdd(&counts[vid], 1u);
}

__global__ void k_blocksum(const unsigned int* __restrict__ counts,
                           unsigned int* __restrict__ bsums) {
    int i = blockIdx.x * SCAN_BS + threadIdx.x;
    int flag = (counts[i] != 0u) ? 1 : 0;
    unsigned long long b = __ballot(flag);
    __shared__ unsigned int wsum[SCAN_BS / 64];
    if ((threadIdx.x & 63) == 0) wsum[threadIdx.x >> 6] = (unsigned)__popcll(b);
    __syncthreads();
    if (threadIdx.x == 0) {
        unsigned s = 0;
        for (int w = 0; w < SCAN_BS / 64; ++w) s += wsum[w];
        bsums[blockIdx.x] = s;
    }
}

__global__ void k_scan_bsums(unsigned int* __restrict__ bsums,
                             unsigned int* __restrict__ scal) {
    __shared__ unsigned int sh[1024];
    int t = threadIdx.x;
    unsigned v = (t < NBLK) ? bsums[t] : 0u;
    sh[t] = v;
    __syncthreads();
    for (int off = 1; off < 1024; off <<= 1) {
        unsigned add = (t >= off) ? sh[t - off] : 0u;
        __syncthreads();
        sh[t] += add;
        __syncthreads();
    }
    if (t < NBLK) bsums[t] = sh[t] - v;
    if (t == NBLK - 1) scal[0] = sh[t];
}

__global__ void k_ranks(const unsigned int* __restrict__ counts,
                        const unsigned int* __restrict__ bsums,
                        int* __restrict__ rank_of, int* __restrict__ vid_of_rank) {
    int i = blockIdx.x * SCAN_BS + threadIdx.x;
    int t = threadIdx.x;
    int flag = (counts[i] != 0u) ? 1 : 0;
    __shared__ unsigned int sh[SCAN_BS];
    sh[t] = (unsigned)flag;
    __syncthreads();
    for (int off = 1; off < SCAN_BS; off <<= 1) {
        unsigned add = (t >= off) ? sh[t - off] : 0u;
        __syncthreads();
        sh[t] += add;
        __syncthreads();
    }
    unsigned rank = bsums[blockIdx.x] + sh[t] - (unsigned)flag;
    int r = (flag && rank < (unsigned)MAX_VOXv) ? (int)rank : -1;
    rank_of[i] = r;
    if (r >= 0) vid_of_rank[r] = i;
}

__global__ void k_append(const float* __restrict__ pf, int N,
                         const int* __restrict__ rank_of,
                         unsigned int* __restrict__ appcnt,
                         float* __restrict__ out) {
    int i = blockIdx.x * blockDim.x + threadIdx.x;
    if (i >= N) return;
    float4 v = reinterpret_cast<const float4*>(pf)[(size_t)i * 2];
    int vid = voxel_id(v.x, v.y, v.z);
    if (vid < 0) return;
    int r = rank_of[vid];
    if (r < 0) return;
    unsigned s = atomicAdd(&appcnt[r], 1u);
    if (s < (unsigned)SLOT_CAP) {
        int* rowi = reinterpret_cast<int*>(out + (size_t)r * (MAX_PTSv * 8));
        rowi[s] = i;
    }
}

__global__ void k_emit(const float* __restrict__ pf,
                       const unsigned int* __restrict__ appcnt,
                       const int* __restrict__ vid_of_rank,
                       const unsigned int* __restrict__ scal,
                       float* __restrict__ out) {
    int r = blockIdx.x;
    int t = threadIdx.x;
    float* row       = out + (size_t)r * (MAX_PTSv * 8);
    float* out_coord = out + VOX_F;
    float* out_num   = out + VOX_F + COORD_F;
    unsigned K = min(scal[0], (unsigned)MAX_VOXv);

    if ((unsigned)r >= K) {
        reinterpret_cast<float4*>(row)[t] = make_float4(0.f, 0.f, 0.f, 0.f);
        if (t == 0) {
            out_coord[(size_t)r * 3 + 0] = 0.f;
            out_coord[(size_t)r * 3 + 1] = 0.f;
            out_coord[(size_t)r * 3 + 2] = 0.f;
            out_num[r] = 0.f;
        }
        return;
    }

    __shared__ int sidx[SLOT_CAP];
    int c = (int)min(appcnt[r], (unsigned)SLOT_CAP);
    const int* rowi = reinterpret_cast<const int*>(row);
    sidx[t] = (t < c) ? rowi[t] : 0x7fffffff;
    __syncthreads();
    int nkeep = c < MAX_PTSv ? c : MAX_PTSv;

    if (t < c) {
        int my = sidx[t];
        int pos = 0;
        for (int j = 0; j < c; ++j) pos += (sidx[j] < my) ? 1 : 0;
        if (pos < MAX_PTSv) {
            const float4* src = reinterpret_cast<const float4*>(pf) + (size_t)my * 2;
            float4 a = src[0];
            float4 b = src[1];
            float4* dst = reinterpret_cast<float4*>(row + pos * 8);
            dst[0] = a;
            dst[1] = b;
        }
    }
    if (t >= nkeep && t < MAX_PTSv) {
        float4* dst = reinterpret_cast<float4*>(row + t * 8);
        dst[0] = make_float4(0.f, 0.f, 0.f, 0.f);
        dst[1] = make_float4(0.f, 0.f, 0.f, 0.f);
    }
    if (t == 0) {
        int vid = vid_of_rank[r];
        int vx = vid % NXv;
        int vy = (vid / NXv) % NYv;
        int vz = vid / (NXv * NYv);
        out_coord[(size_t)r * 3 + 0] = (float)vz;
        out_coord[(size_t)r * 3 + 1] = (float)vy;
        out_coord[(size_t)r * 3 + 2] = (float)vx;
        out_num[r] = (float)nkeep;
    }
}

extern "C" void kernel_launch(void* const* d_in, const int* in_sizes, int n_in,
                              void* d_out, int out_size, void* d_ws, size_t ws_size,
                              hipStream_t stream) {
    const float* pf = (const float*)d_in[0];
    const int N = in_sizes[0] / 8;
    float* out = (float*)d_out;

    // fast-path ws layout (bytes):
    //   [occ u8 215040]           <- zeroed by k_zero
    //   [appcnt u32 160000]       <- zeroed inside blocksum2
    //   [scal 64]                 <- plain store by ranks3
    //   [bsums 4096][rank_of NVOX*4][vid_of_rank MAX_VOX*4][vids N*4]
    //   [slots MAX_VOX*64*4 = 10.24MB]
    const size_t OCC_B  = 215040;
    const size_t APP_B  = (size_t)MAX_VOXv * 4;
    const size_t SCAL_B = 64;
    const size_t HEAD_B = OCC_B + APP_B + SCAL_B;
    const size_t BS_B   = 4096;
    const size_t RANK_B = (size_t)NVOX * 4;
    const size_t VOR_B  = (size_t)MAX_VOXv * 4;
    const size_t VIDS_B = (size_t)N * 4;
    const size_t SLOT_B = (size_t)MAX_VOXv * SLOT_CAP * 4;
    const size_t NEED   = HEAD_B + BS_B + RANK_B + VOR_B + VIDS_B + SLOT_B;

    char* wsb = (char*)d_ws;
    unsigned char* occ        = (unsigned char*)wsb;
    unsigned int* appcnt      = (unsigned int*)(wsb + OCC_B);
    unsigned int* scal        = (unsigned int*)(wsb + OCC_B + APP_B);
    unsigned int* bsums       = (unsigned int*)(wsb + HEAD_B);
    int*          rank_of     = (int*)(wsb + HEAD_B + BS_B);
    int*          vid_of_rank = (int*)(wsb + HEAD_B + BS_B + RANK_B);
    int*          vids        = (int*)(wsb + HEAD_B + BS_B + RANK_B + VOR_B);
    int*          slots       = (int*)(wsb + HEAD_B + BS_B + RANK_B + VOR_B + VIDS_B);

    if (ws_size >= NEED) {
        k_zero<<<210, 256, 0, stream>>>((unsigned int*)occ, (int)(OCC_B / 4));
        k_prep2<<<((N + 1) / 2 + 255) / 256, 256, 0, stream>>>(pf, N, vids, occ);
        k_blocksum2<<<NBLK, SCAN_BS, 0, stream>>>(occ, bsums, appcnt);
        k_ranks3<<<NBLK, SCAN_BS, 0, stream>>>(occ, bsums, scal, rank_of, vid_of_rank);
        k_append2<<<(N + 255) / 256, 256, 0, stream>>>(vids, N, rank_of, appcnt, slots);
        k_emit4<<<MAX_VOXv / 4, SCAN_BS, 0, stream>>>(pf, appcnt, slots, vid_of_rank, scal, out);
        return;
    }

    // fallback: r6 proven layout/path (~2.04 MB)
    unsigned int* wsp          = (unsigned int*)d_ws;
    unsigned int* counts_f     = wsp;
    unsigned int* appcnt_f     = counts_f + NVOX;
    unsigned int* bsums_f      = appcnt_f + MAX_VOXv;
    unsigned int* scal_f       = bsums_f + 1024;
    int*          rank_of_f    = (int*)(scal_f + 4);
    int*          vid_of_rk_f  = rank_of_f + NVOX;

    const int n_zero = NVOX + MAX_VOXv + 1024 + 4;
    k_zero<<<512, 256, 0, stream>>>(wsp, n_zero);
    k_count<<<(N + 255) / 256, 256, 0, stream>>>(pf, N, counts_f);
    k_blocksum<<<NBLK, SCAN_BS, 0, stream>>>(counts_f, bsums_f);
    k_scan_bsums<<<1, 1024, 0, stream>>>(bsums_f, scal_f);
    k_ranks<<<NBLK, SCAN_BS, 0, stream>>>(counts_f, bsums_f, rank_of_f, vid_of_rk_f);
    k_append<<<(N + 255) / 256, 256, 0, stream>>>(pf, N, rank_of_f, appcnt_f, out);
    k_emit<<<MAX_VOXv, 64, 0, stream>>>(pf, appcnt_f, vid_of_rk_f, scal_f, out);
}